// Round 2
// baseline (463.820 us; speedup 1.0000x reference)
//
#include <hip/hip_runtime.h>
#include <hip/hip_bf16.h>
#include <stdint.h>

#define NTOK 2048
#define NB 4
#define DM 256
#define HD 64
#define NE 65536

typedef __bf16 bf16x8 __attribute__((ext_vector_type(8)));
typedef float f32x4 __attribute__((ext_vector_type(4)));

#define MFMA16 __builtin_amdgcn_mfma_f32_16x16x32_bf16

__device__ __forceinline__ unsigned short f2bf(float f) {
    union { float f; uint32_t u; } v; v.f = f;
    return (unsigned short)((v.u + 0x7fffu + ((v.u >> 16) & 1u)) >> 16);
}

// ---------------- casts / weight prep ----------------
__global__ void k_cast_x(const float* __restrict__ x, unsigned short* __restrict__ xb) {
    int i = (blockIdx.x * 256 + threadIdx.x) * 4;
    float4 v = *(const float4*)(x + i);
    ushort4 o;
    o.x = f2bf(v.x); o.y = f2bf(v.y); o.z = f2bf(v.z); o.w = f2bf(v.w);
    *(ushort4*)(xb + i) = o;
}

__global__ void k_prep_w(const float* __restrict__ W0, const float* __restrict__ W1,
                         const float* __restrict__ W2, const float* __restrict__ W3,
                         unsigned short* __restrict__ WT) {
    int sel = blockIdx.y;
    const float* W = sel == 0 ? W0 : sel == 1 ? W1 : sel == 2 ? W2 : W3;
    int e = blockIdx.x * 256 + threadIdx.x;           // e = n*256 + k
    int n = e >> 8, k = e & 255;
    WT[sel * 65536 + e] = f2bf(W[k * 256 + n]);       // WT[n][k] = W[k][n]
}

// ---------------- edge preprocessing (edge_index arrives as int32) ----------------
__global__ void k_edges(const int* __restrict__ ei, uint32_t* __restrict__ counts,
                        uint32_t* __restrict__ ebits) {
    int e = blockIdx.x * 256 + threadIdx.x;
    int r = ei[e];
    int c = ei[NE + e];
    atomicAdd(&counts[r], 1u);
    atomicOr(&ebits[r * 64 + (c >> 5)], 1u << (c & 31));
}

__global__ __launch_bounds__(1024) void k_scan(const uint32_t* __restrict__ cnt,
                                               uint32_t* __restrict__ offs) {
    __shared__ uint32_t a[2][NTOK];
    int t = threadIdx.x;
    a[0][t] = cnt[t]; a[0][t + 1024] = cnt[t + 1024];
    __syncthreads();
    int cur = 0;
    for (int d = 1; d < NTOK; d <<= 1) {
        int nxt = cur ^ 1;
        uint32_t v0 = a[cur][t] + (t >= d ? a[cur][t - d] : 0u);
        int i1 = t + 1024;
        uint32_t v1 = a[cur][i1] + (i1 >= d ? a[cur][i1 - d] : 0u);
        a[nxt][t] = v0; a[nxt][i1] = v1;
        __syncthreads();
        cur = nxt;
    }
    offs[t] = t ? a[cur][t - 1] : 0u;
    offs[t + 1024] = a[cur][t + 1023];
}

__global__ void k_scatter(const int* __restrict__ ei, const uint32_t* __restrict__ offs,
                          uint32_t* __restrict__ cursor, uint32_t* __restrict__ scol) {
    int e = blockIdx.x * 256 + threadIdx.x;
    int r = ei[e];
    int c = ei[NE + e];
    uint32_t p = offs[r] + atomicAdd(&cursor[r], 1u);
    scol[p] = (uint32_t)c;
}

// ---------------- GNN: segment-sum + 2-layer MLP (f64 accumulation) ----------------
__global__ void k_gnn(const float* __restrict__ x, const uint32_t* __restrict__ offs,
                      const uint32_t* __restrict__ cnt, const uint32_t* __restrict__ scol,
                      const float* __restrict__ Wg1, const float* __restrict__ bg1,
                      const float* __restrict__ Wg2, const float* __restrict__ bg2,
                      float* __restrict__ topo) {
    int i = blockIdx.x, t = threadIdx.x;
    double a0 = 0, a1 = 0, a2 = 0, a3 = 0;
    uint32_t e0 = offs[i], e1 = e0 + cnt[i];
    for (uint32_t e = e0; e < e1; ++e) {
        int c = (int)scol[e];
        const float* xp = x + (size_t)c * DM + t;
        a0 += (double)xp[0];
        a1 += (double)xp[NTOK * DM];
        a2 += (double)xp[2 * NTOK * DM];
        a3 += (double)xp[3 * NTOK * DM];
    }
    __shared__ double ag[NB][DM];
    ag[0][t] = a0; ag[1][t] = a1; ag[2][t] = a2; ag[3][t] = a3;
    __syncthreads();
    __shared__ double hp[NB][128];
    if (t < 128) {
        double h0 = (double)bg1[t], h1 = h0, h2 = h0, h3 = h0;
        for (int r = 0; r < DM; ++r) {
            double wv = (double)Wg1[r * 128 + t];
            h0 += ag[0][r] * wv; h1 += ag[1][r] * wv;
            h2 += ag[2][r] * wv; h3 += ag[3][r] * wv;
        }
        double w2 = (double)Wg2[t];
        hp[0][t] = (h0 > 0 ? h0 : 0.0) * w2;
        hp[1][t] = (h1 > 0 ? h1 : 0.0) * w2;
        hp[2][t] = (h2 > 0 ? h2 : 0.0) * w2;
        hp[3][t] = (h3 > 0 ? h3 : 0.0) * w2;
    }
    __syncthreads();
    if (t < NB) {
        double s = 0;
        for (int j = 0; j < 128; ++j) s += hp[t][j];
        topo[t * NTOK + i] = (float)(s + (double)bg2[0]);
    }
}

// ---------------- top-k column mask (stable tie-break = lax.top_k) ----------------
__global__ __launch_bounds__(1024) void k_topk(const float* __restrict__ topo,
                                               uint32_t* __restrict__ colbits) {
    int b = blockIdx.x, t = threadIdx.x;
    __shared__ float sc[NTOK];
    __shared__ uint32_t cb[64];
    sc[t] = topo[b * NTOK + t];
    sc[t + 1024] = topo[b * NTOK + t + 1024];
    if (t < 64) cb[t] = 0u;
    __syncthreads();
    #pragma unroll
    for (int half = 0; half < 2; ++half) {
        int i = t + half * 1024;
        float si = sc[i];
        int rank = 0;
        for (int j = 0; j < NTOK; ++j) {
            float sj = sc[j];
            rank += (sj > si) || (sj == si && j < i);
        }
        if (rank < 1024) atomicOr(&cb[i >> 5], 1u << (i & 31));
    }
    __syncthreads();
    if (t < 64) colbits[b * 64 + t] = cb[t];
}

// ---------------- generic bf16 GEMM: [8192,256] @ W[256,256] + bias ----------------
// MODE 0: bf16 out [M][256]   MODE 1: V^T layout [bh][d][n] bf16   MODE 2: f32 out
template <int MODE>
__global__ __launch_bounds__(256) void k_gemm(const unsigned short* __restrict__ A,
                                              const unsigned short* __restrict__ WT,
                                              const float* __restrict__ bias,
                                              void* __restrict__ out) {
    int lane = threadIdx.x & 63, w = threadIdx.x >> 6;
    int l15 = lane & 15, grp = lane >> 4;
    int mbase = blockIdx.x * 64 + w * 16;
    int nbase = blockIdx.y * 64;
    f32x4 acc0 = {0,0,0,0}, acc1 = {0,0,0,0}, acc2 = {0,0,0,0}, acc3 = {0,0,0,0};
    const unsigned short* ap = A + (size_t)(mbase + l15) * DM + grp * 8;
    const unsigned short* bp = WT + (size_t)(nbase + l15) * DM + grp * 8;
    #pragma unroll
    for (int k0 = 0; k0 < DM; k0 += 32) {
        bf16x8 af = *(const bf16x8*)(ap + k0);
        acc0 = MFMA16(af, *(const bf16x8*)(bp + k0), acc0, 0, 0, 0);
        acc1 = MFMA16(af, *(const bf16x8*)(bp + 16 * DM + k0), acc1, 0, 0, 0);
        acc2 = MFMA16(af, *(const bf16x8*)(bp + 32 * DM + k0), acc2, 0, 0, 0);
        acc3 = MFMA16(af, *(const bf16x8*)(bp + 48 * DM + k0), acc3, 0, 0, 0);
    }
    f32x4 accs[4] = {acc0, acc1, acc2, acc3};
    #pragma unroll
    for (int ct = 0; ct < 4; ++ct) {
        #pragma unroll
        for (int r = 0; r < 4; ++r) {
            int m = mbase + grp * 4 + r;
            int n = nbase + ct * 16 + l15;
            float v = accs[ct][r] + bias[n];
            if (MODE == 0) {
                ((unsigned short*)out)[(size_t)m * DM + n] = f2bf(v);
            } else if (MODE == 1) {
                int b = m >> 11, q = m & 2047, h = n >> 6, d = n & 63;
                ((unsigned short*)out)[(size_t)((((b << 2) + h) << 6) + d) * NTOK + q] = f2bf(v);
            } else {
                ((float*)out)[(size_t)m * DM + n] = v;
            }
        }
    }
}

// ---------------- flash attention with bitmask (S^T = K·Q^T trick) ----------------
__global__ __launch_bounds__(256) void k_attn(const unsigned short* __restrict__ Q,
                                              const unsigned short* __restrict__ K,
                                              const unsigned short* __restrict__ VT,
                                              const uint32_t* __restrict__ ebits,
                                              const uint32_t* __restrict__ colbits,
                                              unsigned short* __restrict__ aout) {
    int lane = threadIdx.x & 63, w = threadIdx.x >> 6;
    int l15 = lane & 15, grp = lane >> 4;
    int bh = blockIdx.y, b = bh >> 2, h = bh & 3;
    int q = blockIdx.x * 64 + w * 16 + l15;

    const unsigned short* qp = Q + (size_t)(b * NTOK + q) * DM + h * HD + grp * 8;
    bf16x8 qf0 = *(const bf16x8*)(qp);
    bf16x8 qf1 = *(const bf16x8*)(qp + 32);
    const unsigned short* kp = K + (size_t)b * NTOK * DM + h * HD + grp * 8;
    const unsigned short* vp = VT + (size_t)(bh * HD) * NTOK + grp * 8;
    const uint32_t* eb = ebits + q * 64;
    const uint32_t* cbp = colbits + b * 64;

    f32x4 o0 = {0,0,0,0}, o1 = {0,0,0,0}, o2 = {0,0,0,0}, o3 = {0,0,0,0};
    float mrun = -1e30f, lrun = 0.f;

    for (int kb = 0; kb < NTOK; kb += 32) {
        const unsigned short* kp0 = kp + (size_t)(kb + l15) * DM;
        const unsigned short* kp1 = kp0 + 16 * DM;
        f32x4 st0 = {0,0,0,0}, st1 = {0,0,0,0};
        st0 = MFMA16(*(const bf16x8*)(kp0), qf0, st0, 0, 0, 0);
        st0 = MFMA16(*(const bf16x8*)(kp0 + 32), qf1, st0, 0, 0, 0);
        st1 = MFMA16(*(const bf16x8*)(kp1), qf0, st1, 0, 0, 0);
        st1 = MFMA16(*(const bf16x8*)(kp1 + 32), qf1, st1, 0, 0, 0);

        uint32_t mw = eb[kb >> 5] | cbp[kb >> 5];
        float s[8];
        #pragma unroll
        for (int r = 0; r < 4; ++r) {
            int p0 = grp * 4 + r;
            s[r]     = ((mw >> p0) & 1u)          ? st0[r] * 0.125f : -1e30f;
            s[4 + r] = ((mw >> (16 + p0)) & 1u)   ? st1[r] * 0.125f : -1e30f;
        }
        float tm = s[0];
        #pragma unroll
        for (int j = 1; j < 8; ++j) tm = fmaxf(tm, s[j]);
        tm = fmaxf(tm, __shfl_xor(tm, 16));
        tm = fmaxf(tm, __shfl_xor(tm, 32));
        float mnew = fmaxf(mrun, tm);
        float esc = __expf(mrun - mnew);
        float p[8], ps = 0.f;
        #pragma unroll
        for (int j = 0; j < 8; ++j) { p[j] = __expf(s[j] - mnew); ps += p[j]; }
        ps += __shfl_xor(ps, 16);
        ps += __shfl_xor(ps, 32);
        lrun = lrun * esc + ps;
        mrun = mnew;
        o0 *= esc; o1 *= esc; o2 *= esc; o3 *= esc;

        // pack P to bf16 pairs (keys 2w,2w+1) and redistribute into B-fragment layout
        uint32_t pk00 = ((uint32_t)f2bf(p[1]) << 16) | f2bf(p[0]);
        uint32_t pk01 = ((uint32_t)f2bf(p[3]) << 16) | f2bf(p[2]);
        uint32_t pk10 = ((uint32_t)f2bf(p[5]) << 16) | f2bf(p[4]);
        uint32_t pk11 = ((uint32_t)f2bf(p[7]) << 16) | f2bf(p[6]);
        union { uint32_t u[4]; bf16x8 v; } pf;
        #pragma unroll
        for (int wi = 0; wi < 4; ++wi) {
            int src = (((grp * 2 + (wi >> 1)) & 3) << 4) | l15;
            uint32_t lo = (uint32_t)__shfl((int)((wi & 1) ? pk01 : pk00), src);
            uint32_t hi = (uint32_t)__shfl((int)((wi & 1) ? pk11 : pk10), src);
            pf.u[wi] = (lane >= 32) ? hi : lo;
        }

        const unsigned short* vk = vp + kb;
        o0 = MFMA16(*(const bf16x8*)(vk + (size_t)(l15) * NTOK),      pf.v, o0, 0, 0, 0);
        o1 = MFMA16(*(const bf16x8*)(vk + (size_t)(16 + l15) * NTOK), pf.v, o1, 0, 0, 0);
        o2 = MFMA16(*(const bf16x8*)(vk + (size_t)(32 + l15) * NTOK), pf.v, o2, 0, 0, 0);
        o3 = MFMA16(*(const bf16x8*)(vk + (size_t)(48 + l15) * NTOK), pf.v, o3, 0, 0, 0);
    }
    float inv = 1.f / lrun;
    unsigned short* op = aout + (size_t)(b * NTOK + q) * DM + h * HD;
    #pragma unroll
    for (int r = 0; r < 4; ++r) {
        op[grp * 4 + r]      = f2bf(o0[r] * inv);
        op[16 + grp * 4 + r] = f2bf(o1[r] * inv);
        op[32 + grp * 4 + r] = f2bf(o2[r] * inv);
        op[48 + grp * 4 + r] = f2bf(o3[r] * inv);
    }
}

// ---------------- mask4 output writer (runs LAST; overwrites scratch region) ----------------
__global__ void k_mask4(const uint32_t* __restrict__ ebits, const uint32_t* __restrict__ colbits,
                        float* __restrict__ mout) {
    int idx = blockIdx.x * 256 + threadIdx.x;   // 2,097,152 threads
    int b = idx >> 19;
    int rem = idx & 524287;
    int i = rem >> 8;
    int j = (rem & 255) << 3;
    uint32_t mw = ebits[i * 64 + (j >> 5)] | colbits[b * 64 + (j >> 5)];
    int sh = j & 31;
    float4 v0, v1;
    v0.x = ((mw >> sh) & 1u) ? 1.f : 0.f;
    v0.y = ((mw >> (sh + 1)) & 1u) ? 1.f : 0.f;
    v0.z = ((mw >> (sh + 2)) & 1u) ? 1.f : 0.f;
    v0.w = ((mw >> (sh + 3)) & 1u) ? 1.f : 0.f;
    v1.x = ((mw >> (sh + 4)) & 1u) ? 1.f : 0.f;
    v1.y = ((mw >> (sh + 5)) & 1u) ? 1.f : 0.f;
    v1.z = ((mw >> (sh + 6)) & 1u) ? 1.f : 0.f;
    v1.w = ((mw >> (sh + 7)) & 1u) ? 1.f : 0.f;
    size_t base = (((size_t)b * 4) * NTOK + i) * NTOK + j;
    #pragma unroll
    for (int hh = 0; hh < 4; ++hh) {
        float* p = mout + base + (size_t)hh * NTOK * NTOK;
        *(float4*)p = v0;
        *(float4*)(p + 4) = v1;
    }
}

extern "C" void kernel_launch(void* const* d_in, const int* in_sizes, int n_in,
                              void* d_out, int out_size, void* d_ws, size_t ws_size,
                              hipStream_t stream) {
    const float* x   = (const float*)d_in[0];
    const int*   ei  = (const int*)d_in[1];          // int64 in reference -> int32 here
    const float* Wq  = (const float*)d_in[2];
    const float* bq  = (const float*)d_in[3];
    const float* Wk  = (const float*)d_in[4];
    const float* bk  = (const float*)d_in[5];
    const float* Wv  = (const float*)d_in[6];
    const float* bv  = (const float*)d_in[7];
    const float* Wo  = (const float*)d_in[8];
    const float* bo  = (const float*)d_in[9];
    const float* Wg1 = (const float*)d_in[10];
    const float* bg1 = (const float*)d_in[11];
    const float* Wg2 = (const float*)d_in[12];
    const float* bg2 = (const float*)d_in[13];

    float* out0  = (float*)d_out;
    float* mask4 = out0 + (size_t)NB * NTOK * DM;

    // Large scratch lives in the mask4 output region (256 MB); k_mask4 runs last
    // and fully overwrites it each call, so graph replays stay deterministic.
    uint8_t* big = (uint8_t*)mask4;
    unsigned short* xbf   = (unsigned short*)(big);              // 4 MB
    unsigned short* qbf   = (unsigned short*)(big + (4u << 20)); // 4 MB
    unsigned short* kbf   = (unsigned short*)(big + (8u << 20)); // 4 MB
    unsigned short* vt    = (unsigned short*)(big + (12u << 20));// 4 MB
    unsigned short* aoutb = (unsigned short*)(big + (16u << 20));// 4 MB
    unsigned short* wt    = (unsigned short*)(big + (20u << 20));// 512 KB
    uint32_t*       scol  = (uint32_t*)(big + (21u << 20));      // 256 KB

    // Small scratch in d_ws (~572 KB total)
    uint8_t* ws = (uint8_t*)d_ws;
    uint32_t* counts  = (uint32_t*)(ws);               // 8 KB (atomic, needs zero)
    uint32_t* cursor  = (uint32_t*)(ws + (8u << 10));  // 8 KB (atomic, needs zero)
    uint32_t* ebits   = (uint32_t*)(ws + (16u << 10)); // 512 KB (atomic, needs zero)
    uint32_t* offs    = (uint32_t*)(ws + (528u << 10));// 8 KB (fully written)
    uint32_t* colbits = (uint32_t*)(ws + (536u << 10));// 256 B (fully written)
    float*    topo    = (float*)(ws + (540u << 10));   // 32 KB (fully written)

    hipMemsetAsync(ws, 0, 528u << 10, stream);

    k_cast_x<<<2048, 256, 0, stream>>>(x, xbf);
    k_prep_w<<<dim3(256, 4), 256, 0, stream>>>(Wq, Wk, Wv, Wo, wt);
    k_edges<<<256, 256, 0, stream>>>(ei, counts, ebits);
    k_scan<<<1, 1024, 0, stream>>>(counts, offs);
    k_scatter<<<256, 256, 0, stream>>>(ei, offs, cursor, scol);
    k_gnn<<<2048, 256, 0, stream>>>(x, offs, counts, scol, Wg1, bg1, Wg2, bg2, topo);
    k_topk<<<4, 1024, 0, stream>>>(topo, colbits);
    k_gemm<0><<<dim3(128, 4), 256, 0, stream>>>(xbf, wt,          bq, qbf);
    k_gemm<0><<<dim3(128, 4), 256, 0, stream>>>(xbf, wt + 65536,  bk, kbf);
    k_gemm<1><<<dim3(128, 4), 256, 0, stream>>>(xbf, wt + 131072, bv, vt);
    k_attn<<<dim3(32, 16), 256, 0, stream>>>(qbf, kbf, vt, ebits, colbits, aoutb);
    k_gemm<2><<<dim3(128, 4), 256, 0, stream>>>(aoutb, wt + 196608, bo, out0);
    k_mask4<<<8192, 256, 0, stream>>>(ebits, colbits, mask4);
}

// Round 3
// 356.197 us; speedup vs baseline: 1.3021x; 1.3021x over previous
//
#include <hip/hip_runtime.h>
#include <hip/hip_bf16.h>
#include <stdint.h>

#define NTOK 2048
#define NB 4
#define DM 256
#define HD 64
#define NE 65536

typedef __bf16 bf16x8 __attribute__((ext_vector_type(8)));
typedef float f32x4 __attribute__((ext_vector_type(4)));

#define MFMA16 __builtin_amdgcn_mfma_f32_16x16x32_bf16

__device__ __forceinline__ unsigned short f2bf(float f) {
    union { float f; uint32_t u; } v; v.f = f;
    return (unsigned short)((v.u + 0x7fffu + ((v.u >> 16) & 1u)) >> 16);
}

// ---------------- workspace zeroing (replaces pathological hipMemsetAsync) ----------------
__global__ void k_zero(float4* __restrict__ p) {
    p[blockIdx.x * 256 + threadIdx.x] = float4{0.f, 0.f, 0.f, 0.f};
}

// ---------------- casts / weight prep ----------------
__global__ void k_cast_x(const float* __restrict__ x, unsigned short* __restrict__ xb) {
    int i = (blockIdx.x * 256 + threadIdx.x) * 4;
    float4 v = *(const float4*)(x + i);
    ushort4 o;
    o.x = f2bf(v.x); o.y = f2bf(v.y); o.z = f2bf(v.z); o.w = f2bf(v.w);
    *(ushort4*)(xb + i) = o;
}

__global__ void k_prep_w(const float* __restrict__ W0, const float* __restrict__ W1,
                         const float* __restrict__ W2, const float* __restrict__ W3,
                         unsigned short* __restrict__ WT) {
    int sel = blockIdx.y;
    const float* W = sel == 0 ? W0 : sel == 1 ? W1 : sel == 2 ? W2 : W3;
    int e = blockIdx.x * 256 + threadIdx.x;           // e = n*256 + k
    int n = e >> 8, k = e & 255;
    WT[sel * 65536 + e] = f2bf(W[k * 256 + n]);       // WT[n][k] = W[k][n]
}

// ---------------- edge preprocessing (edge_index arrives as int32) ----------------
__global__ void k_edges(const int* __restrict__ ei, uint32_t* __restrict__ counts,
                        uint32_t* __restrict__ ebits) {
    int e = blockIdx.x * 256 + threadIdx.x;
    int r = ei[e];
    int c = ei[NE + e];
    atomicAdd(&counts[r], 1u);
    atomicOr(&ebits[r * 64 + (c >> 5)], 1u << (c & 31));
}

__global__ __launch_bounds__(1024) void k_scan(const uint32_t* __restrict__ cnt,
                                               uint32_t* __restrict__ offs) {
    __shared__ uint32_t a[2][NTOK];
    int t = threadIdx.x;
    a[0][t] = cnt[t]; a[0][t + 1024] = cnt[t + 1024];
    __syncthreads();
    int cur = 0;
    for (int d = 1; d < NTOK; d <<= 1) {
        int nxt = cur ^ 1;
        uint32_t v0 = a[cur][t] + (t >= d ? a[cur][t - d] : 0u);
        int i1 = t + 1024;
        uint32_t v1 = a[cur][i1] + (i1 >= d ? a[cur][i1 - d] : 0u);
        a[nxt][t] = v0; a[nxt][i1] = v1;
        __syncthreads();
        cur = nxt;
    }
    offs[t] = t ? a[cur][t - 1] : 0u;
    offs[t + 1024] = a[cur][t + 1023];
}

__global__ void k_scatter(const int* __restrict__ ei, const uint32_t* __restrict__ offs,
                          uint32_t* __restrict__ cursor, uint32_t* __restrict__ scol) {
    int e = blockIdx.x * 256 + threadIdx.x;
    int r = ei[e];
    int c = ei[NE + e];
    uint32_t p = offs[r] + atomicAdd(&cursor[r], 1u);
    scol[p] = (uint32_t)c;
}

// ---------------- GNN: segment-sum + 2-layer MLP (f64 accumulation) ----------------
__global__ void k_gnn(const float* __restrict__ x, const uint32_t* __restrict__ offs,
                      const uint32_t* __restrict__ cnt, const uint32_t* __restrict__ scol,
                      const float* __restrict__ Wg1, const float* __restrict__ bg1,
                      const float* __restrict__ Wg2, const float* __restrict__ bg2,
                      float* __restrict__ topo) {
    int i = blockIdx.x, t = threadIdx.x;
    double a0 = 0, a1 = 0, a2 = 0, a3 = 0;
    uint32_t e0 = offs[i], e1 = e0 + cnt[i];
    for (uint32_t e = e0; e < e1; ++e) {
        int c = (int)scol[e];
        const float* xp = x + (size_t)c * DM + t;
        a0 += (double)xp[0];
        a1 += (double)xp[NTOK * DM];
        a2 += (double)xp[2 * NTOK * DM];
        a3 += (double)xp[3 * NTOK * DM];
    }
    __shared__ double ag[NB][DM];
    ag[0][t] = a0; ag[1][t] = a1; ag[2][t] = a2; ag[3][t] = a3;
    __syncthreads();
    __shared__ double hp[NB][128];
    if (t < 128) {
        double h0 = (double)bg1[t], h1 = h0, h2 = h0, h3 = h0;
        for (int r = 0; r < DM; ++r) {
            double wv = (double)Wg1[r * 128 + t];
            h0 += ag[0][r] * wv; h1 += ag[1][r] * wv;
            h2 += ag[2][r] * wv; h3 += ag[3][r] * wv;
        }
        double w2 = (double)Wg2[t];
        hp[0][t] = (h0 > 0 ? h0 : 0.0) * w2;
        hp[1][t] = (h1 > 0 ? h1 : 0.0) * w2;
        hp[2][t] = (h2 > 0 ? h2 : 0.0) * w2;
        hp[3][t] = (h3 > 0 ? h3 : 0.0) * w2;
    }
    __syncthreads();
    if (t < NB) {
        double s = 0;
        for (int j = 0; j < 128; ++j) s += hp[t][j];
        topo[t * NTOK + i] = (float)(s + (double)bg2[0]);
    }
}

// ---------------- top-k column mask (stable tie-break = lax.top_k), parallel ----------------
__global__ __launch_bounds__(256) void k_topk(const float* __restrict__ topo,
                                              uint32_t* __restrict__ colbits) {
    int b = blockIdx.y, t = threadIdx.x;
    int i = blockIdx.x * 256 + t;
    __shared__ float sc[NTOK];
    for (int j = t; j < NTOK; j += 256) sc[j] = topo[b * NTOK + j];
    __syncthreads();
    float si = sc[i];
    int rank = 0;
    #pragma unroll 4
    for (int j = 0; j < NTOK; ++j) {
        float sj = sc[j];
        rank += (sj > si) || (sj == si && j < i);
    }
    unsigned long long m = __ballot(rank < 1024);
    int lane = t & 63;
    if (lane == 0)       colbits[b * 64 + (i >> 5)] = (uint32_t)m;
    else if (lane == 32) colbits[b * 64 + (i >> 5)] = (uint32_t)(m >> 32);
}

// ---------------- generic bf16 GEMM: [8192,256] @ W[256,256] + bias ----------------
// MODE 0: bf16 out [M][256]   MODE 1: V^T layout [bh][d][n] bf16   MODE 2: f32 out
template <int MODE>
__global__ __launch_bounds__(256) void k_gemm(const unsigned short* __restrict__ A,
                                              const unsigned short* __restrict__ WT,
                                              const float* __restrict__ bias,
                                              void* __restrict__ out) {
    int lane = threadIdx.x & 63, w = threadIdx.x >> 6;
    int l15 = lane & 15, grp = lane >> 4;
    int mbase = blockIdx.x * 64 + w * 16;
    int nbase = blockIdx.y * 64;
    f32x4 acc0 = {0,0,0,0}, acc1 = {0,0,0,0}, acc2 = {0,0,0,0}, acc3 = {0,0,0,0};
    const unsigned short* ap = A + (size_t)(mbase + l15) * DM + grp * 8;
    const unsigned short* bp = WT + (size_t)(nbase + l15) * DM + grp * 8;
    #pragma unroll
    for (int k0 = 0; k0 < DM; k0 += 32) {
        bf16x8 af = *(const bf16x8*)(ap + k0);
        acc0 = MFMA16(af, *(const bf16x8*)(bp + k0), acc0, 0, 0, 0);
        acc1 = MFMA16(af, *(const bf16x8*)(bp + 16 * DM + k0), acc1, 0, 0, 0);
        acc2 = MFMA16(af, *(const bf16x8*)(bp + 32 * DM + k0), acc2, 0, 0, 0);
        acc3 = MFMA16(af, *(const bf16x8*)(bp + 48 * DM + k0), acc3, 0, 0, 0);
    }
    f32x4 accs[4] = {acc0, acc1, acc2, acc3};
    #pragma unroll
    for (int ct = 0; ct < 4; ++ct) {
        #pragma unroll
        for (int r = 0; r < 4; ++r) {
            int m = mbase + grp * 4 + r;
            int n = nbase + ct * 16 + l15;
            float v = accs[ct][r] + bias[n];
            if (MODE == 0) {
                ((unsigned short*)out)[(size_t)m * DM + n] = f2bf(v);
            } else if (MODE == 1) {
                int b = m >> 11, q = m & 2047, h = n >> 6, d = n & 63;
                ((unsigned short*)out)[(size_t)((((b << 2) + h) << 6) + d) * NTOK + q] = f2bf(v);
            } else {
                ((float*)out)[(size_t)m * DM + n] = v;
            }
        }
    }
}

// ---------------- flash attention with bitmask (S^T = K·Q^T trick) ----------------
__global__ __launch_bounds__(256) void k_attn(const unsigned short* __restrict__ Q,
                                              const unsigned short* __restrict__ K,
                                              const unsigned short* __restrict__ VT,
                                              const uint32_t* __restrict__ ebits,
                                              const uint32_t* __restrict__ colbits,
                                              unsigned short* __restrict__ aout) {
    int lane = threadIdx.x & 63, w = threadIdx.x >> 6;
    int l15 = lane & 15, grp = lane >> 4;
    int bh = blockIdx.y, b = bh >> 2, h = bh & 3;
    int q = blockIdx.x * 64 + w * 16 + l15;

    const unsigned short* qp = Q + (size_t)(b * NTOK + q) * DM + h * HD + grp * 8;
    bf16x8 qf0 = *(const bf16x8*)(qp);
    bf16x8 qf1 = *(const bf16x8*)(qp + 32);
    const unsigned short* kp = K + (size_t)b * NTOK * DM + h * HD + grp * 8;
    const unsigned short* vp = VT + (size_t)(bh * HD) * NTOK + grp * 8;
    const uint32_t* eb = ebits + q * 64;
    const uint32_t* cbp = colbits + b * 64;

    f32x4 o0 = {0,0,0,0}, o1 = {0,0,0,0}, o2 = {0,0,0,0}, o3 = {0,0,0,0};
    float mrun = -1e30f, lrun = 0.f;

    for (int kb = 0; kb < NTOK; kb += 32) {
        const unsigned short* kp0 = kp + (size_t)(kb + l15) * DM;
        const unsigned short* kp1 = kp0 + 16 * DM;
        f32x4 st0 = {0,0,0,0}, st1 = {0,0,0,0};
        st0 = MFMA16(*(const bf16x8*)(kp0), qf0, st0, 0, 0, 0);
        st0 = MFMA16(*(const bf16x8*)(kp0 + 32), qf1, st0, 0, 0, 0);
        st1 = MFMA16(*(const bf16x8*)(kp1), qf0, st1, 0, 0, 0);
        st1 = MFMA16(*(const bf16x8*)(kp1 + 32), qf1, st1, 0, 0, 0);

        uint32_t mw = eb[kb >> 5] | cbp[kb >> 5];
        float s[8];
        #pragma unroll
        for (int r = 0; r < 4; ++r) {
            int p0 = grp * 4 + r;
            s[r]     = ((mw >> p0) & 1u)          ? st0[r] * 0.125f : -1e30f;
            s[4 + r] = ((mw >> (16 + p0)) & 1u)   ? st1[r] * 0.125f : -1e30f;
        }
        float tm = s[0];
        #pragma unroll
        for (int j = 1; j < 8; ++j) tm = fmaxf(tm, s[j]);
        tm = fmaxf(tm, __shfl_xor(tm, 16));
        tm = fmaxf(tm, __shfl_xor(tm, 32));
        float mnew = fmaxf(mrun, tm);
        float esc = __expf(mrun - mnew);
        float p[8], ps = 0.f;
        #pragma unroll
        for (int j = 0; j < 8; ++j) { p[j] = __expf(s[j] - mnew); ps += p[j]; }
        ps += __shfl_xor(ps, 16);
        ps += __shfl_xor(ps, 32);
        lrun = lrun * esc + ps;
        mrun = mnew;
        o0 *= esc; o1 *= esc; o2 *= esc; o3 *= esc;

        // pack P to bf16 pairs (keys 2w,2w+1) and redistribute into B-fragment layout
        uint32_t pk00 = ((uint32_t)f2bf(p[1]) << 16) | f2bf(p[0]);
        uint32_t pk01 = ((uint32_t)f2bf(p[3]) << 16) | f2bf(p[2]);
        uint32_t pk10 = ((uint32_t)f2bf(p[5]) << 16) | f2bf(p[4]);
        uint32_t pk11 = ((uint32_t)f2bf(p[7]) << 16) | f2bf(p[6]);
        union { uint32_t u[4]; bf16x8 v; } pf;
        #pragma unroll
        for (int wi = 0; wi < 4; ++wi) {
            int src = (((grp * 2 + (wi >> 1)) & 3) << 4) | l15;
            uint32_t lo = (uint32_t)__shfl((int)((wi & 1) ? pk01 : pk00), src);
            uint32_t hi = (uint32_t)__shfl((int)((wi & 1) ? pk11 : pk10), src);
            pf.u[wi] = (lane >= 32) ? hi : lo;
        }

        const unsigned short* vk = vp + kb;
        o0 = MFMA16(*(const bf16x8*)(vk + (size_t)(l15) * NTOK),      pf.v, o0, 0, 0, 0);
        o1 = MFMA16(*(const bf16x8*)(vk + (size_t)(16 + l15) * NTOK), pf.v, o1, 0, 0, 0);
        o2 = MFMA16(*(const bf16x8*)(vk + (size_t)(32 + l15) * NTOK), pf.v, o2, 0, 0, 0);
        o3 = MFMA16(*(const bf16x8*)(vk + (size_t)(48 + l15) * NTOK), pf.v, o3, 0, 0, 0);
    }
    float inv = 1.f / lrun;
    unsigned short* op = aout + (size_t)(b * NTOK + q) * DM + h * HD;
    #pragma unroll
    for (int r = 0; r < 4; ++r) {
        op[grp * 4 + r]      = f2bf(o0[r] * inv);
        op[16 + grp * 4 + r] = f2bf(o1[r] * inv);
        op[32 + grp * 4 + r] = f2bf(o2[r] * inv);
        op[48 + grp * 4 + r] = f2bf(o3[r] * inv);
    }
}

// ---------------- mask4 output writer (runs LAST; overwrites scratch region) ----------------
__global__ void k_mask4(const uint32_t* __restrict__ ebits, const uint32_t* __restrict__ colbits,
                        float* __restrict__ mout) {
    int idx = blockIdx.x * 256 + threadIdx.x;   // 2,097,152 threads
    int b = idx >> 19;
    int rem = idx & 524287;
    int i = rem >> 8;
    int j = (rem & 255) << 3;
    uint32_t mw = ebits[i * 64 + (j >> 5)] | colbits[b * 64 + (j >> 5)];
    int sh = j & 31;
    float4 v0, v1;
    v0.x = ((mw >> sh) & 1u) ? 1.f : 0.f;
    v0.y = ((mw >> (sh + 1)) & 1u) ? 1.f : 0.f;
    v0.z = ((mw >> (sh + 2)) & 1u) ? 1.f : 0.f;
    v0.w = ((mw >> (sh + 3)) & 1u) ? 1.f : 0.f;
    v1.x = ((mw >> (sh + 4)) & 1u) ? 1.f : 0.f;
    v1.y = ((mw >> (sh + 5)) & 1u) ? 1.f : 0.f;
    v1.z = ((mw >> (sh + 6)) & 1u) ? 1.f : 0.f;
    v1.w = ((mw >> (sh + 7)) & 1u) ? 1.f : 0.f;
    size_t base = (((size_t)b * 4) * NTOK + i) * NTOK + j;
    #pragma unroll
    for (int hh = 0; hh < 4; ++hh) {
        float* p = mout + base + (size_t)hh * NTOK * NTOK;
        *(float4*)p = v0;
        *(float4*)(p + 4) = v1;
    }
}

extern "C" void kernel_launch(void* const* d_in, const int* in_sizes, int n_in,
                              void* d_out, int out_size, void* d_ws, size_t ws_size,
                              hipStream_t stream) {
    const float* x   = (const float*)d_in[0];
    const int*   ei  = (const int*)d_in[1];          // int64 in reference -> int32 here
    const float* Wq  = (const float*)d_in[2];
    const float* bq  = (const float*)d_in[3];
    const float* Wk  = (const float*)d_in[4];
    const float* bk  = (const float*)d_in[5];
    const float* Wv  = (const float*)d_in[6];
    const float* bv  = (const float*)d_in[7];
    const float* Wo  = (const float*)d_in[8];
    const float* bo  = (const float*)d_in[9];
    const float* Wg1 = (const float*)d_in[10];
    const float* bg1 = (const float*)d_in[11];
    const float* Wg2 = (const float*)d_in[12];
    const float* bg2 = (const float*)d_in[13];

    float* out0  = (float*)d_out;
    float* mask4 = out0 + (size_t)NB * NTOK * DM;

    // Large scratch lives in the mask4 output region (256 MB); k_mask4 runs last
    // and fully overwrites it each call, so graph replays stay deterministic.
    uint8_t* big = (uint8_t*)mask4;
    unsigned short* xbf   = (unsigned short*)(big);              // 4 MB
    unsigned short* qbf   = (unsigned short*)(big + (4u << 20)); // 4 MB
    unsigned short* kbf   = (unsigned short*)(big + (8u << 20)); // 4 MB
    unsigned short* vt    = (unsigned short*)(big + (12u << 20));// 4 MB
    unsigned short* aoutb = (unsigned short*)(big + (16u << 20));// 4 MB
    unsigned short* wt    = (unsigned short*)(big + (20u << 20));// 512 KB
    uint32_t*       scol  = (uint32_t*)(big + (21u << 20));      // 256 KB

    // Small scratch in d_ws (~572 KB total)
    uint8_t* ws = (uint8_t*)d_ws;
    uint32_t* counts  = (uint32_t*)(ws);               // 8 KB (atomic, needs zero)
    uint32_t* cursor  = (uint32_t*)(ws + (8u << 10));  // 8 KB (atomic, needs zero)
    uint32_t* ebits   = (uint32_t*)(ws + (16u << 10)); // 512 KB (atomic, needs zero)
    uint32_t* offs    = (uint32_t*)(ws + (528u << 10));// 8 KB (fully written)
    uint32_t* colbits = (uint32_t*)(ws + (536u << 10));// 256 B (fully written)
    float*    topo    = (float*)(ws + (540u << 10));   // 32 KB (fully written)

    k_zero<<<132, 256, 0, stream>>>((float4*)ws);      // zero counts/cursor/ebits (528 KB)

    k_cast_x<<<2048, 256, 0, stream>>>(x, xbf);
    k_prep_w<<<dim3(256, 4), 256, 0, stream>>>(Wq, Wk, Wv, Wo, wt);
    k_edges<<<256, 256, 0, stream>>>(ei, counts, ebits);
    k_scan<<<1, 1024, 0, stream>>>(counts, offs);
    k_scatter<<<256, 256, 0, stream>>>(ei, offs, cursor, scol);
    k_gnn<<<2048, 256, 0, stream>>>(x, offs, counts, scol, Wg1, bg1, Wg2, bg2, topo);
    k_topk<<<dim3(8, 4), 256, 0, stream>>>(topo, colbits);
    k_gemm<0><<<dim3(128, 4), 256, 0, stream>>>(xbf, wt,          bq, qbf);
    k_gemm<0><<<dim3(128, 4), 256, 0, stream>>>(xbf, wt + 65536,  bk, kbf);
    k_gemm<1><<<dim3(128, 4), 256, 0, stream>>>(xbf, wt + 131072, bv, vt);
    k_attn<<<dim3(32, 16), 256, 0, stream>>>(qbf, kbf, vt, ebits, colbits, aoutb);
    k_gemm<2><<<dim3(128, 4), 256, 0, stream>>>(aoutb, wt + 196608, bo, out0);
    k_mask4<<<8192, 256, 0, stream>>>(ebits, colbits, mask4);
}

// Round 4
// 340.773 us; speedup vs baseline: 1.3611x; 1.0453x over previous
//
#include <hip/hip_runtime.h>
#include <hip/hip_bf16.h>
#include <stdint.h>

#define NTOK 2048
#define NB 4
#define DM 256
#define HD 64
#define NE 65536

typedef __bf16 bf16x8 __attribute__((ext_vector_type(8)));
typedef float f32x4 __attribute__((ext_vector_type(4)));

#define MFMA16 __builtin_amdgcn_mfma_f32_16x16x32_bf16

__device__ __forceinline__ unsigned short f2bf(float f) {
    union { float f; uint32_t u; } v; v.f = f;
    return (unsigned short)((v.u + 0x7fffu + ((v.u >> 16) & 1u)) >> 16);
}

// ---------------- F0: fused ws-zero + x cast + weight transpose ----------------
// blocks [0,132): zero 528 KB of ws; [132,2180): cast x->bf16; [2180,3204): W^T
__global__ void k_prep(const float* __restrict__ x, unsigned short* __restrict__ xb,
                       const float* __restrict__ W0, const float* __restrict__ W1,
                       const float* __restrict__ W2, const float* __restrict__ W3,
                       unsigned short* __restrict__ WT, float4* __restrict__ wsz) {
    int bid = blockIdx.x, t = threadIdx.x;
    if (bid < 132) {
        wsz[bid * 256 + t] = float4{0.f, 0.f, 0.f, 0.f};
    } else if (bid < 2180) {
        int i = ((bid - 132) * 256 + t) * 4;
        float4 v = *(const float4*)(x + i);
        ushort4 o;
        o.x = f2bf(v.x); o.y = f2bf(v.y); o.z = f2bf(v.z); o.w = f2bf(v.w);
        *(ushort4*)(xb + i) = o;
    } else {
        int b2 = bid - 2180;                       // [0,1024)
        int sel = b2 >> 8;
        const float* W = sel == 0 ? W0 : sel == 1 ? W1 : sel == 2 ? W2 : W3;
        int e = (b2 & 255) * 256 + t;              // e = n*256 + k
        int n = e >> 8, k = e & 255;
        WT[sel * 65536 + e] = f2bf(W[k * 256 + n]);
    }
}

// ---------------- edge preprocessing (edge_index arrives as int32) ----------------
__global__ void k_edges(const int* __restrict__ ei, uint32_t* __restrict__ counts,
                        uint32_t* __restrict__ ebits) {
    int e = blockIdx.x * 256 + threadIdx.x;
    int r = ei[e];
    int c = ei[NE + e];
    atomicAdd(&counts[r], 1u);
    atomicOr(&ebits[r * 64 + (c >> 5)], 1u << (c & 31));
}

__global__ __launch_bounds__(1024) void k_scan(const uint32_t* __restrict__ cnt,
                                               uint32_t* __restrict__ offs) {
    __shared__ uint32_t a[2][NTOK];
    int t = threadIdx.x;
    a[0][t] = cnt[t]; a[0][t + 1024] = cnt[t + 1024];
    __syncthreads();
    int cur = 0;
    for (int d = 1; d < NTOK; d <<= 1) {
        int nxt = cur ^ 1;
        uint32_t v0 = a[cur][t] + (t >= d ? a[cur][t - d] : 0u);
        int i1 = t + 1024;
        uint32_t v1 = a[cur][i1] + (i1 >= d ? a[cur][i1 - d] : 0u);
        a[nxt][t] = v0; a[nxt][i1] = v1;
        __syncthreads();
        cur = nxt;
    }
    offs[t] = t ? a[cur][t - 1] : 0u;
    offs[t + 1024] = a[cur][t + 1023];
}

__global__ void k_scatter(const int* __restrict__ ei, const uint32_t* __restrict__ offs,
                          uint32_t* __restrict__ cursor, uint32_t* __restrict__ scol) {
    int e = blockIdx.x * 256 + threadIdx.x;
    int r = ei[e];
    int c = ei[NE + e];
    uint32_t p = offs[r] + atomicAdd(&cursor[r], 1u);
    scol[p] = (uint32_t)c;
}

// ---------------- GNN: segment-sum + 2-layer MLP (f64 accumulation, 2-way ILP) ----------------
__global__ void k_gnn(const float* __restrict__ x, const uint32_t* __restrict__ offs,
                      const uint32_t* __restrict__ cnt, const uint32_t* __restrict__ scol,
                      const float* __restrict__ Wg1, const float* __restrict__ bg1,
                      const float* __restrict__ Wg2, const float* __restrict__ bg2,
                      float* __restrict__ topo) {
    const int S = NTOK * DM;
    int i = blockIdx.x, t = threadIdx.x;
    double a0 = 0, a1 = 0, a2 = 0, a3 = 0;   // parity-0 chains (4 batches)
    double c0 = 0, c1 = 0, c2 = 0, c3 = 0;   // parity-1 chains
    uint32_t e0 = offs[i], e1 = e0 + cnt[i];
    uint32_t e = e0;
    for (; e + 1 < e1; e += 2) {
        const float* p0 = x + (size_t)scol[e] * DM + t;
        const float* p1 = x + (size_t)scol[e + 1] * DM + t;
        a0 += (double)p0[0];     c0 += (double)p1[0];
        a1 += (double)p0[S];     c1 += (double)p1[S];
        a2 += (double)p0[2 * S]; c2 += (double)p1[2 * S];
        a3 += (double)p0[3 * S]; c3 += (double)p1[3 * S];
    }
    if (e < e1) {
        const float* p0 = x + (size_t)scol[e] * DM + t;
        a0 += (double)p0[0];
        a1 += (double)p0[S];
        a2 += (double)p0[2 * S];
        a3 += (double)p0[3 * S];
    }
    __shared__ double ag[NB][DM];
    ag[0][t] = a0 + c0; ag[1][t] = a1 + c1; ag[2][t] = a2 + c2; ag[3][t] = a3 + c3;
    __syncthreads();
    // MLP: all 256 threads: pair = t>>7 covers batches {2p, 2p+1}, col = t&127
    __shared__ double hp[NB][128];
    {
        int col = t & 127, pair = t >> 7;
        double h0 = (double)bg1[col], h1 = h0;
        const double* agA = ag[2 * pair];
        const double* agB = ag[2 * pair + 1];
        for (int r = 0; r < DM; ++r) {
            double wv = (double)Wg1[r * 128 + col];
            h0 += agA[r] * wv; h1 += agB[r] * wv;
        }
        double w2 = (double)Wg2[col];
        hp[2 * pair][col]     = (h0 > 0 ? h0 : 0.0) * w2;
        hp[2 * pair + 1][col] = (h1 > 0 ? h1 : 0.0) * w2;
    }
    __syncthreads();
    // reduce 128 values per batch: batch = t>>6, lane = t&63
    {
        int batch = t >> 6, lane = t & 63;
        double s = hp[batch][lane] + hp[batch][lane + 64];
        #pragma unroll
        for (int d = 32; d >= 1; d >>= 1) s += __shfl_xor(s, d);
        if (lane == 0) topo[batch * NTOK + i] = (float)(s + (double)bg2[0]);
    }
}

// ---------------- top-k column mask (stable tie-break = lax.top_k), float4 scan ----------------
__global__ __launch_bounds__(256) void k_topk(const float* __restrict__ topo,
                                              uint32_t* __restrict__ colbits) {
    int b = blockIdx.y, t = threadIdx.x;
    int i = blockIdx.x * 256 + t;
    __shared__ float4 sc4[NTOK / 4];
    const float4* tp = (const float4*)(topo + b * NTOK);
    for (int j = t; j < NTOK / 4; j += 256) sc4[j] = tp[j];
    __syncthreads();
    float si = ((const float*)sc4)[i];
    int rank = 0;
    #pragma unroll 2
    for (int jj = 0; jj < NTOK / 4; ++jj) {
        float4 v = sc4[jj];
        int j0 = jj * 4;
        rank += (v.x > si) || (v.x == si && (j0    ) < i);
        rank += (v.y > si) || (v.y == si && (j0 + 1) < i);
        rank += (v.z > si) || (v.z == si && (j0 + 2) < i);
        rank += (v.w > si) || (v.w == si && (j0 + 3) < i);
    }
    unsigned long long m = __ballot(rank < 1024);
    int lane = t & 63;
    if (lane == 0)       colbits[b * 64 + (i >> 5)] = (uint32_t)m;
    else if (lane == 32) colbits[b * 64 + (i >> 5)] = (uint32_t)(m >> 32);
}

// ---------------- fused QKV GEMM: z selects weight/bias/output; V gets V^T layout ----------------
__global__ __launch_bounds__(256) void k_gemm_qkv(const unsigned short* __restrict__ A,
                                                  const unsigned short* __restrict__ WT,
                                                  const float* __restrict__ bq,
                                                  const float* __restrict__ bk,
                                                  const float* __restrict__ bv,
                                                  unsigned short* __restrict__ qo,
                                                  unsigned short* __restrict__ ko,
                                                  unsigned short* __restrict__ vo) {
    int z = blockIdx.z;
    const unsigned short* W = WT + z * 65536;
    const float* bias = z == 0 ? bq : z == 1 ? bk : bv;
    unsigned short* out = z == 0 ? qo : z == 1 ? ko : vo;

    int lane = threadIdx.x & 63, w = threadIdx.x >> 6;
    int l15 = lane & 15, grp = lane >> 4;
    int mbase = blockIdx.x * 64 + w * 16;
    int nbase = blockIdx.y * 64;
    f32x4 acc0 = {0,0,0,0}, acc1 = {0,0,0,0}, acc2 = {0,0,0,0}, acc3 = {0,0,0,0};
    const unsigned short* ap = A + (size_t)(mbase + l15) * DM + grp * 8;
    const unsigned short* bp = W + (size_t)(nbase + l15) * DM + grp * 8;
    #pragma unroll
    for (int k0 = 0; k0 < DM; k0 += 32) {
        bf16x8 af = *(const bf16x8*)(ap + k0);
        acc0 = MFMA16(af, *(const bf16x8*)(bp + k0), acc0, 0, 0, 0);
        acc1 = MFMA16(af, *(const bf16x8*)(bp + 16 * DM + k0), acc1, 0, 0, 0);
        acc2 = MFMA16(af, *(const bf16x8*)(bp + 32 * DM + k0), acc2, 0, 0, 0);
        acc3 = MFMA16(af, *(const bf16x8*)(bp + 48 * DM + k0), acc3, 0, 0, 0);
    }
    f32x4 accs[4] = {acc0, acc1, acc2, acc3};
    #pragma unroll
    for (int ct = 0; ct < 4; ++ct) {
        #pragma unroll
        for (int r = 0; r < 4; ++r) {
            int m = mbase + grp * 4 + r;
            int n = nbase + ct * 16 + l15;
            float v = accs[ct][r] + bias[n];
            if (z < 2) {
                out[(size_t)m * DM + n] = f2bf(v);
            } else {
                int b = m >> 11, q = m & 2047, h = n >> 6, d = n & 63;
                out[(size_t)((((b << 2) + h) << 6) + d) * NTOK + q] = f2bf(v);
            }
        }
    }
}

// ---------------- output projection GEMM (f32 out) ----------------
__global__ __launch_bounds__(256) void k_gemm_o(const unsigned short* __restrict__ A,
                                                const unsigned short* __restrict__ WT,
                                                const float* __restrict__ bias,
                                                float* __restrict__ out) {
    int lane = threadIdx.x & 63, w = threadIdx.x >> 6;
    int l15 = lane & 15, grp = lane >> 4;
    int mbase = blockIdx.x * 64 + w * 16;
    int nbase = blockIdx.y * 64;
    f32x4 acc0 = {0,0,0,0}, acc1 = {0,0,0,0}, acc2 = {0,0,0,0}, acc3 = {0,0,0,0};
    const unsigned short* ap = A + (size_t)(mbase + l15) * DM + grp * 8;
    const unsigned short* bp = WT + (size_t)(nbase + l15) * DM + grp * 8;
    #pragma unroll
    for (int k0 = 0; k0 < DM; k0 += 32) {
        bf16x8 af = *(const bf16x8*)(ap + k0);
        acc0 = MFMA16(af, *(const bf16x8*)(bp + k0), acc0, 0, 0, 0);
        acc1 = MFMA16(af, *(const bf16x8*)(bp + 16 * DM + k0), acc1, 0, 0, 0);
        acc2 = MFMA16(af, *(const bf16x8*)(bp + 32 * DM + k0), acc2, 0, 0, 0);
        acc3 = MFMA16(af, *(const bf16x8*)(bp + 48 * DM + k0), acc3, 0, 0, 0);
    }
    f32x4 accs[4] = {acc0, acc1, acc2, acc3};
    #pragma unroll
    for (int ct = 0; ct < 4; ++ct) {
        #pragma unroll
        for (int r = 0; r < 4; ++r) {
            int m = mbase + grp * 4 + r;
            int n = nbase + ct * 16 + l15;
            out[(size_t)m * DM + n] = accs[ct][r] + bias[n];
        }
    }
}

// ---------------- flash attention with bitmask (S^T = K·Q^T trick) ----------------
__global__ __launch_bounds__(256) void k_attn(const unsigned short* __restrict__ Q,
                                              const unsigned short* __restrict__ K,
                                              const unsigned short* __restrict__ VT,
                                              const uint32_t* __restrict__ ebits,
                                              const uint32_t* __restrict__ colbits,
                                              unsigned short* __restrict__ aout) {
    int lane = threadIdx.x & 63, w = threadIdx.x >> 6;
    int l15 = lane & 15, grp = lane >> 4;
    int bh = blockIdx.y, b = bh >> 2, h = bh & 3;
    int q = blockIdx.x * 64 + w * 16 + l15;

    const unsigned short* qp = Q + (size_t)(b * NTOK + q) * DM + h * HD + grp * 8;
    bf16x8 qf0 = *(const bf16x8*)(qp);
    bf16x8 qf1 = *(const bf16x8*)(qp + 32);
    const unsigned short* kp = K + (size_t)b * NTOK * DM + h * HD + grp * 8;
    const unsigned short* vp = VT + (size_t)(bh * HD) * NTOK + grp * 8;
    const uint32_t* eb = ebits + q * 64;
    const uint32_t* cbp = colbits + b * 64;

    f32x4 o0 = {0,0,0,0}, o1 = {0,0,0,0}, o2 = {0,0,0,0}, o3 = {0,0,0,0};
    float mrun = -1e30f, lrun = 0.f;

    for (int kb = 0; kb < NTOK; kb += 32) {
        const unsigned short* kp0 = kp + (size_t)(kb + l15) * DM;
        const unsigned short* kp1 = kp0 + 16 * DM;
        f32x4 st0 = {0,0,0,0}, st1 = {0,0,0,0};
        st0 = MFMA16(*(const bf16x8*)(kp0), qf0, st0, 0, 0, 0);
        st0 = MFMA16(*(const bf16x8*)(kp0 + 32), qf1, st0, 0, 0, 0);
        st1 = MFMA16(*(const bf16x8*)(kp1), qf0, st1, 0, 0, 0);
        st1 = MFMA16(*(const bf16x8*)(kp1 + 32), qf1, st1, 0, 0, 0);

        uint32_t mw = eb[kb >> 5] | cbp[kb >> 5];
        float s[8];
        #pragma unroll
        for (int r = 0; r < 4; ++r) {
            int p0 = grp * 4 + r;
            s[r]     = ((mw >> p0) & 1u)          ? st0[r] * 0.125f : -1e30f;
            s[4 + r] = ((mw >> (16 + p0)) & 1u)   ? st1[r] * 0.125f : -1e30f;
        }
        float tm = s[0];
        #pragma unroll
        for (int j = 1; j < 8; ++j) tm = fmaxf(tm, s[j]);
        tm = fmaxf(tm, __shfl_xor(tm, 16));
        tm = fmaxf(tm, __shfl_xor(tm, 32));
        float mnew = fmaxf(mrun, tm);
        float esc = __expf(mrun - mnew);
        float p[8], ps = 0.f;
        #pragma unroll
        for (int j = 0; j < 8; ++j) { p[j] = __expf(s[j] - mnew); ps += p[j]; }
        ps += __shfl_xor(ps, 16);
        ps += __shfl_xor(ps, 32);
        lrun = lrun * esc + ps;
        mrun = mnew;
        o0 *= esc; o1 *= esc; o2 *= esc; o3 *= esc;

        uint32_t pk00 = ((uint32_t)f2bf(p[1]) << 16) | f2bf(p[0]);
        uint32_t pk01 = ((uint32_t)f2bf(p[3]) << 16) | f2bf(p[2]);
        uint32_t pk10 = ((uint32_t)f2bf(p[5]) << 16) | f2bf(p[4]);
        uint32_t pk11 = ((uint32_t)f2bf(p[7]) << 16) | f2bf(p[6]);
        union { uint32_t u[4]; bf16x8 v; } pf;
        #pragma unroll
        for (int wi = 0; wi < 4; ++wi) {
            int src = (((grp * 2 + (wi >> 1)) & 3) << 4) | l15;
            uint32_t lo = (uint32_t)__shfl((int)((wi & 1) ? pk01 : pk00), src);
            uint32_t hi = (uint32_t)__shfl((int)((wi & 1) ? pk11 : pk10), src);
            pf.u[wi] = (lane >= 32) ? hi : lo;
        }

        const unsigned short* vk = vp + kb;
        o0 = MFMA16(*(const bf16x8*)(vk + (size_t)(l15) * NTOK),      pf.v, o0, 0, 0, 0);
        o1 = MFMA16(*(const bf16x8*)(vk + (size_t)(16 + l15) * NTOK), pf.v, o1, 0, 0, 0);
        o2 = MFMA16(*(const bf16x8*)(vk + (size_t)(32 + l15) * NTOK), pf.v, o2, 0, 0, 0);
        o3 = MFMA16(*(const bf16x8*)(vk + (size_t)(48 + l15) * NTOK), pf.v, o3, 0, 0, 0);
    }
    float inv = 1.f / lrun;
    unsigned short* op = aout + (size_t)(b * NTOK + q) * DM + h * HD;
    #pragma unroll
    for (int r = 0; r < 4; ++r) {
        op[grp * 4 + r]      = f2bf(o0[r] * inv);
        op[16 + grp * 4 + r] = f2bf(o1[r] * inv);
        op[32 + grp * 4 + r] = f2bf(o2[r] * inv);
        op[48 + grp * 4 + r] = f2bf(o3[r] * inv);
    }
}

// ---------------- mask4 output writer (runs LAST; overwrites scratch region) ----------------
__global__ void k_mask4(const uint32_t* __restrict__ ebits, const uint32_t* __restrict__ colbits,
                        float* __restrict__ mout) {
    int idx = blockIdx.x * 256 + threadIdx.x;   // 2,097,152 threads
    int b = idx >> 19;
    int rem = idx & 524287;
    int i = rem >> 8;
    int j = (rem & 255) << 3;
    uint32_t mw = ebits[i * 64 + (j >> 5)] | colbits[b * 64 + (j >> 5)];
    int sh = j & 31;
    float4 v0, v1;
    v0.x = ((mw >> sh) & 1u) ? 1.f : 0.f;
    v0.y = ((mw >> (sh + 1)) & 1u) ? 1.f : 0.f;
    v0.z = ((mw >> (sh + 2)) & 1u) ? 1.f : 0.f;
    v0.w = ((mw >> (sh + 3)) & 1u) ? 1.f : 0.f;
    v1.x = ((mw >> (sh + 4)) & 1u) ? 1.f : 0.f;
    v1.y = ((mw >> (sh + 5)) & 1u) ? 1.f : 0.f;
    v1.z = ((mw >> (sh + 6)) & 1u) ? 1.f : 0.f;
    v1.w = ((mw >> (sh + 7)) & 1u) ? 1.f : 0.f;
    size_t base = (((size_t)b * 4) * NTOK + i) * NTOK + j;
    #pragma unroll
    for (int hh = 0; hh < 4; ++hh) {
        float* p = mout + base + (size_t)hh * NTOK * NTOK;
        *(float4*)p = v0;
        *(float4*)(p + 4) = v1;
    }
}

extern "C" void kernel_launch(void* const* d_in, const int* in_sizes, int n_in,
                              void* d_out, int out_size, void* d_ws, size_t ws_size,
                              hipStream_t stream) {
    const float* x   = (const float*)d_in[0];
    const int*   ei  = (const int*)d_in[1];          // int64 in reference -> int32 here
    const float* Wq  = (const float*)d_in[2];
    const float* bq  = (const float*)d_in[3];
    const float* Wk  = (const float*)d_in[4];
    const float* bk  = (const float*)d_in[5];
    const float* Wv  = (const float*)d_in[6];
    const float* bv  = (const float*)d_in[7];
    const float* Wo  = (const float*)d_in[8];
    const float* bo  = (const float*)d_in[9];
    const float* Wg1 = (const float*)d_in[10];
    const float* bg1 = (const float*)d_in[11];
    const float* Wg2 = (const float*)d_in[12];
    const float* bg2 = (const float*)d_in[13];

    float* out0  = (float*)d_out;
    float* mask4 = out0 + (size_t)NB * NTOK * DM;

    // Large scratch lives in the mask4 output region (256 MB); k_mask4 runs last
    // and fully overwrites it each call, so graph replays stay deterministic.
    uint8_t* big = (uint8_t*)mask4;
    unsigned short* xbf   = (unsigned short*)(big);              // 4 MB
    unsigned short* qbf   = (unsigned short*)(big + (4u << 20)); // 4 MB
    unsigned short* kbf   = (unsigned short*)(big + (8u << 20)); // 4 MB
    unsigned short* vt    = (unsigned short*)(big + (12u << 20));// 4 MB
    unsigned short* aoutb = (unsigned short*)(big + (16u << 20));// 4 MB
    unsigned short* wt    = (unsigned short*)(big + (20u << 20));// 512 KB
    uint32_t*       scol  = (uint32_t*)(big + (21u << 20));      // 256 KB

    // Small scratch in d_ws (~572 KB total)
    uint8_t* ws = (uint8_t*)d_ws;
    uint32_t* counts  = (uint32_t*)(ws);               // 8 KB (atomic, needs zero)
    uint32_t* cursor  = (uint32_t*)(ws + (8u << 10));  // 8 KB (atomic, needs zero)
    uint32_t* ebits   = (uint32_t*)(ws + (16u << 10)); // 512 KB (atomic, needs zero)
    uint32_t* offs    = (uint32_t*)(ws + (528u << 10));// 8 KB (fully written)
    uint32_t* colbits = (uint32_t*)(ws + (536u << 10));// 256 B (fully written)
    float*    topo    = (float*)(ws + (540u << 10));   // 32 KB (fully written)

    k_prep<<<3204, 256, 0, stream>>>(x, xbf, Wq, Wk, Wv, Wo, wt, (float4*)ws);
    k_edges<<<256, 256, 0, stream>>>(ei, counts, ebits);
    k_scan<<<1, 1024, 0, stream>>>(counts, offs);
    k_scatter<<<256, 256, 0, stream>>>(ei, offs, cursor, scol);
    k_gnn<<<2048, 256, 0, stream>>>(x, offs, counts, scol, Wg1, bg1, Wg2, bg2, topo);
    k_topk<<<dim3(8, 4), 256, 0, stream>>>(topo, colbits);
    k_gemm_qkv<<<dim3(128, 4, 3), 256, 0, stream>>>(xbf, wt, bq, bk, bv, qbf, kbf, vt);
    k_attn<<<dim3(32, 16), 256, 0, stream>>>(qbf, kbf, vt, ebits, colbits, aoutb);
    k_gemm_o<<<dim3(128, 4), 256, 0, stream>>>(aoutb, wt + 196608, bo, out0);
    k_mask4<<<8192, 256, 0, stream>>>(ebits, colbits, mask4);
}

// Round 5
// 329.862 us; speedup vs baseline: 1.4061x; 1.0331x over previous
//
#include <hip/hip_runtime.h>
#include <hip/hip_bf16.h>
#include <stdint.h>

#define NTOK 2048
#define NB 4
#define DM 256
#define HD 64
#define NE 65536
#define SCAP 128
#define DEFER_ROWS 3360   // rows of mask4 holding scratch (26.25 MB > 21.5 MB used)

typedef __bf16 bf16x8 __attribute__((ext_vector_type(8)));
typedef float f32x4 __attribute__((ext_vector_type(4)));

#define MFMA16 __builtin_amdgcn_mfma_f32_16x16x32_bf16

__device__ __forceinline__ unsigned short f2bf(float f) {
    union { float f; uint32_t u; } v; v.f = f;
    return (unsigned short)((v.u + 0x7fffu + ((v.u >> 16) & 1u)) >> 16);
}

// ---------------- F0: fused ws-zero + x cast + weight transpose ----------------
// blocks [0,132): zero 528 KB of ws; [132,2180): cast x->bf16; [2180,3204): W^T
__global__ void k_prep(const float* __restrict__ x, unsigned short* __restrict__ xb,
                       const float* __restrict__ W0, const float* __restrict__ W1,
                       const float* __restrict__ W2, const float* __restrict__ W3,
                       unsigned short* __restrict__ WT, float4* __restrict__ wsz) {
    int bid = blockIdx.x, t = threadIdx.x;
    if (bid < 132) {
        wsz[bid * 256 + t] = float4{0.f, 0.f, 0.f, 0.f};
    } else if (bid < 2180) {
        int i = ((bid - 132) * 256 + t) * 4;
        float4 v = *(const float4*)(x + i);
        ushort4 o;
        o.x = f2bf(v.x); o.y = f2bf(v.y); o.z = f2bf(v.z); o.w = f2bf(v.w);
        *(ushort4*)(xb + i) = o;
    } else {
        int b2 = bid - 2180;                       // [0,1024)
        int sel = b2 >> 8;
        const float* W = sel == 0 ? W0 : sel == 1 ? W1 : sel == 2 ? W2 : W3;
        int e = (b2 & 255) * 256 + t;              // e = n*256 + k
        int n = e >> 8, k = e & 255;
        WT[sel * 65536 + e] = f2bf(W[k * 256 + n]);
    }
}

// ---------------- edges: fused count + bucket-scatter + bitmap ----------------
__global__ void k_edges(const int* __restrict__ ei, uint32_t* __restrict__ cursor,
                        uint32_t* __restrict__ scol, uint32_t* __restrict__ ebits) {
    int e = blockIdx.x * 256 + threadIdx.x;
    int r = ei[e];
    int c = ei[NE + e];
    uint32_t slot = atomicAdd(&cursor[r], 1u);
    if (slot < SCAP) scol[r * SCAP + slot] = (uint32_t)c;
    atomicOr(&ebits[r * 64 + (c >> 5)], 1u << (c & 31));
}

// ---------------- fused: GNN (blocks [0,2048)) + QKV GEMM (blocks [2048,3584)) ----------------
__global__ __launch_bounds__(256) void k_gnn_qkv(
    const float* __restrict__ x, const uint32_t* __restrict__ cursor,
    const uint32_t* __restrict__ scol,
    const float* __restrict__ Wg1, const float* __restrict__ bg1,
    const float* __restrict__ Wg2, const float* __restrict__ bg2,
    float* __restrict__ topo,
    const unsigned short* __restrict__ xbf, const unsigned short* __restrict__ WT,
    const float* __restrict__ bq, const float* __restrict__ bk, const float* __restrict__ bv,
    unsigned short* __restrict__ qo, unsigned short* __restrict__ ko,
    unsigned short* __restrict__ vo) {
    int bid = blockIdx.x, t = threadIdx.x;
    if (bid < 2048) {
        // ---- GNN: segment-sum + 2-layer MLP, f64 accumulation, 2-way ILP ----
        const int S = NTOK * DM;
        int i = bid;
        double a0 = 0, a1 = 0, a2 = 0, a3 = 0;
        double c0 = 0, c1 = 0, c2 = 0, c3 = 0;
        uint32_t cnt = cursor[i]; if (cnt > SCAP) cnt = SCAP;
        const uint32_t* sc = scol + i * SCAP;
        uint32_t e = 0;
        for (; e + 1 < cnt; e += 2) {
            const float* p0 = x + (size_t)sc[e] * DM + t;
            const float* p1 = x + (size_t)sc[e + 1] * DM + t;
            a0 += (double)p0[0];     c0 += (double)p1[0];
            a1 += (double)p0[S];     c1 += (double)p1[S];
            a2 += (double)p0[2 * S]; c2 += (double)p1[2 * S];
            a3 += (double)p0[3 * S]; c3 += (double)p1[3 * S];
        }
        if (e < cnt) {
            const float* p0 = x + (size_t)sc[e] * DM + t;
            a0 += (double)p0[0];
            a1 += (double)p0[S];
            a2 += (double)p0[2 * S];
            a3 += (double)p0[3 * S];
        }
        __shared__ double ag[NB][DM];
        ag[0][t] = a0 + c0; ag[1][t] = a1 + c1; ag[2][t] = a2 + c2; ag[3][t] = a3 + c3;
        __syncthreads();
        __shared__ double hp[NB][128];
        {
            int col = t & 127, pair = t >> 7;
            double h0 = (double)bg1[col], h1 = h0;
            const double* agA = ag[2 * pair];
            const double* agB = ag[2 * pair + 1];
            for (int r = 0; r < DM; ++r) {
                double wv = (double)Wg1[r * 128 + col];
                h0 += agA[r] * wv; h1 += agB[r] * wv;
            }
            double w2 = (double)Wg2[col];
            hp[2 * pair][col]     = (h0 > 0 ? h0 : 0.0) * w2;
            hp[2 * pair + 1][col] = (h1 > 0 ? h1 : 0.0) * w2;
        }
        __syncthreads();
        {
            int batch = t >> 6, lane = t & 63;
            double s = hp[batch][lane] + hp[batch][lane + 64];
            #pragma unroll
            for (int d = 32; d >= 1; d >>= 1) s += __shfl_xor(s, d);
            if (lane == 0) topo[batch * NTOK + i] = (float)(s + (double)bg2[0]);
        }
    } else {
        // ---- QKV GEMM: z = weight select, V gets V^T layout ----
        int b2 = bid - 2048;
        int z = b2 >> 9, r2 = b2 & 511;
        const unsigned short* W = WT + z * 65536;
        const float* bias = z == 0 ? bq : z == 1 ? bk : bv;
        unsigned short* out = z == 0 ? qo : z == 1 ? ko : vo;

        int lane = t & 63, w = t >> 6;
        int l15 = lane & 15, grp = lane >> 4;
        int mbase = (r2 & 127) * 64 + w * 16;
        int nbase = (r2 >> 7) * 64;
        f32x4 acc0 = {0,0,0,0}, acc1 = {0,0,0,0}, acc2 = {0,0,0,0}, acc3 = {0,0,0,0};
        const unsigned short* ap = xbf + (size_t)(mbase + l15) * DM + grp * 8;
        const unsigned short* bp = W + (size_t)(nbase + l15) * DM + grp * 8;
        #pragma unroll
        for (int k0 = 0; k0 < DM; k0 += 32) {
            bf16x8 af = *(const bf16x8*)(ap + k0);
            acc0 = MFMA16(af, *(const bf16x8*)(bp + k0), acc0, 0, 0, 0);
            acc1 = MFMA16(af, *(const bf16x8*)(bp + 16 * DM + k0), acc1, 0, 0, 0);
            acc2 = MFMA16(af, *(const bf16x8*)(bp + 32 * DM + k0), acc2, 0, 0, 0);
            acc3 = MFMA16(af, *(const bf16x8*)(bp + 48 * DM + k0), acc3, 0, 0, 0);
        }
        f32x4 accs[4] = {acc0, acc1, acc2, acc3};
        #pragma unroll
        for (int ct = 0; ct < 4; ++ct) {
            #pragma unroll
            for (int r = 0; r < 4; ++r) {
                int m = mbase + grp * 4 + r;
                int n = nbase + ct * 16 + l15;
                float v = accs[ct][r] + bias[n];
                if (z < 2) {
                    out[(size_t)m * DM + n] = f2bf(v);
                } else {
                    int b = m >> 11, q = m & 2047, h = n >> 6, d = n & 63;
                    out[(size_t)((((b << 2) + h) << 6) + d) * NTOK + q] = f2bf(v);
                }
            }
        }
    }
}

// ---------------- top-k column mask (stable tie-break = lax.top_k), float4 scan ----------------
__global__ __launch_bounds__(256) void k_topk(const float* __restrict__ topo,
                                              uint32_t* __restrict__ colbits) {
    int b = blockIdx.y, t = threadIdx.x;
    int i = blockIdx.x * 256 + t;
    __shared__ float4 sc4[NTOK / 4];
    const float4* tp = (const float4*)(topo + b * NTOK);
    for (int j = t; j < NTOK / 4; j += 256) sc4[j] = tp[j];
    __syncthreads();
    float si = ((const float*)sc4)[i];
    int rank = 0;
    #pragma unroll 2
    for (int jj = 0; jj < NTOK / 4; ++jj) {
        float4 v = sc4[jj];
        int j0 = jj * 4;
        rank += (v.x > si) || (v.x == si && (j0    ) < i);
        rank += (v.y > si) || (v.y == si && (j0 + 1) < i);
        rank += (v.z > si) || (v.z == si && (j0 + 2) < i);
        rank += (v.w > si) || (v.w == si && (j0 + 3) < i);
    }
    unsigned long long m = __ballot(rank < 1024);
    int lane = t & 63;
    if (lane == 0)       colbits[b * 64 + (i >> 5)] = (uint32_t)m;
    else if (lane == 32) colbits[b * 64 + (i >> 5)] = (uint32_t)(m >> 32);
}

// ---------------- mask4 row writer (one block = one [b,h,i] row, 8 KB) ----------------
__device__ __forceinline__ void mask_row(int rowidx, const uint32_t* __restrict__ eb,
                                         const uint32_t* __restrict__ cb,
                                         float* __restrict__ mout) {
    int t = threadIdx.x;
    int b = rowidx >> 13;          // 8192 rows per batch (4 heads x 2048)
    int i = rowidx & 2047;
    int j0 = t << 3;
    uint32_t mw = eb[i * 64 + (j0 >> 5)] | cb[b * 64 + (j0 >> 5)];
    int sh = j0 & 31;
    float4 v0, v1;
    v0.x = ((mw >> sh) & 1u) ? 1.f : 0.f;
    v0.y = ((mw >> (sh + 1)) & 1u) ? 1.f : 0.f;
    v0.z = ((mw >> (sh + 2)) & 1u) ? 1.f : 0.f;
    v0.w = ((mw >> (sh + 3)) & 1u) ? 1.f : 0.f;
    v1.x = ((mw >> (sh + 4)) & 1u) ? 1.f : 0.f;
    v1.y = ((mw >> (sh + 5)) & 1u) ? 1.f : 0.f;
    v1.z = ((mw >> (sh + 6)) & 1u) ? 1.f : 0.f;
    v1.w = ((mw >> (sh + 7)) & 1u) ? 1.f : 0.f;
    float* p = mout + (size_t)rowidx * NTOK + j0;
    *(float4*)p = v0;
    *(float4*)(p + 4) = v1;
}

// ---------------- fused: attention (blocks [0,512)) + mask4 rows >= DEFER_ROWS ----------------
__global__ __launch_bounds__(256) void k_attn_mask4(const unsigned short* __restrict__ Q,
                                                    const unsigned short* __restrict__ K,
                                                    const unsigned short* __restrict__ VT,
                                                    const uint32_t* __restrict__ ebits,
                                                    const uint32_t* __restrict__ colbits,
                                                    unsigned short* __restrict__ aout,
                                                    float* __restrict__ mout) {
    int bid = blockIdx.x;
    if (bid >= 512) {
        mask_row(bid - 512 + DEFER_ROWS, ebits, colbits, mout);
        return;
    }
    int lane = threadIdx.x & 63, w = threadIdx.x >> 6;
    int l15 = lane & 15, grp = lane >> 4;
    int bh = bid >> 5, b = bh >> 2, h = bh & 3;
    int q = (bid & 31) * 64 + w * 16 + l15;

    const unsigned short* qp = Q + (size_t)(b * NTOK + q) * DM + h * HD + grp * 8;
    bf16x8 qf0 = *(const bf16x8*)(qp);
    bf16x8 qf1 = *(const bf16x8*)(qp + 32);
    const unsigned short* kp = K + (size_t)b * NTOK * DM + h * HD + grp * 8;
    const unsigned short* vp = VT + (size_t)(bh * HD) * NTOK + grp * 8;
    const uint32_t* eb = ebits + q * 64;
    const uint32_t* cbp = colbits + b * 64;

    f32x4 o0 = {0,0,0,0}, o1 = {0,0,0,0}, o2 = {0,0,0,0}, o3 = {0,0,0,0};
    float mrun = -1e30f, lrun = 0.f;

    for (int kb = 0; kb < NTOK; kb += 32) {
        const unsigned short* kp0 = kp + (size_t)(kb + l15) * DM;
        const unsigned short* kp1 = kp0 + 16 * DM;
        f32x4 st0 = {0,0,0,0}, st1 = {0,0,0,0};
        st0 = MFMA16(*(const bf16x8*)(kp0), qf0, st0, 0, 0, 0);
        st0 = MFMA16(*(const bf16x8*)(kp0 + 32), qf1, st0, 0, 0, 0);
        st1 = MFMA16(*(const bf16x8*)(kp1), qf0, st1, 0, 0, 0);
        st1 = MFMA16(*(const bf16x8*)(kp1 + 32), qf1, st1, 0, 0, 0);

        uint32_t mw = eb[kb >> 5] | cbp[kb >> 5];
        float s[8];
        #pragma unroll
        for (int r = 0; r < 4; ++r) {
            int p0 = grp * 4 + r;
            s[r]     = ((mw >> p0) & 1u)          ? st0[r] * 0.125f : -1e30f;
            s[4 + r] = ((mw >> (16 + p0)) & 1u)   ? st1[r] * 0.125f : -1e30f;
        }
        float tm = s[0];
        #pragma unroll
        for (int j = 1; j < 8; ++j) tm = fmaxf(tm, s[j]);
        tm = fmaxf(tm, __shfl_xor(tm, 16));
        tm = fmaxf(tm, __shfl_xor(tm, 32));
        float mnew = fmaxf(mrun, tm);
        float esc = __expf(mrun - mnew);
        float p[8], ps = 0.f;
        #pragma unroll
        for (int j = 0; j < 8; ++j) { p[j] = __expf(s[j] - mnew); ps += p[j]; }
        ps += __shfl_xor(ps, 16);
        ps += __shfl_xor(ps, 32);
        lrun = lrun * esc + ps;
        mrun = mnew;
        o0 *= esc; o1 *= esc; o2 *= esc; o3 *= esc;

        uint32_t pk00 = ((uint32_t)f2bf(p[1]) << 16) | f2bf(p[0]);
        uint32_t pk01 = ((uint32_t)f2bf(p[3]) << 16) | f2bf(p[2]);
        uint32_t pk10 = ((uint32_t)f2bf(p[5]) << 16) | f2bf(p[4]);
        uint32_t pk11 = ((uint32_t)f2bf(p[7]) << 16) | f2bf(p[6]);
        union { uint32_t u[4]; bf16x8 v; } pf;
        #pragma unroll
        for (int wi = 0; wi < 4; ++wi) {
            int src = (((grp * 2 + (wi >> 1)) & 3) << 4) | l15;
            uint32_t lo = (uint32_t)__shfl((int)((wi & 1) ? pk01 : pk00), src);
            uint32_t hi = (uint32_t)__shfl((int)((wi & 1) ? pk11 : pk10), src);
            pf.u[wi] = (lane >= 32) ? hi : lo;
        }

        const unsigned short* vk = vp + kb;
        o0 = MFMA16(*(const bf16x8*)(vk + (size_t)(l15) * NTOK),      pf.v, o0, 0, 0, 0);
        o1 = MFMA16(*(const bf16x8*)(vk + (size_t)(16 + l15) * NTOK), pf.v, o1, 0, 0, 0);
        o2 = MFMA16(*(const bf16x8*)(vk + (size_t)(32 + l15) * NTOK), pf.v, o2, 0, 0, 0);
        o3 = MFMA16(*(const bf16x8*)(vk + (size_t)(48 + l15) * NTOK), pf.v, o3, 0, 0, 0);
    }
    float inv = 1.f / lrun;
    unsigned short* op = aout + (size_t)(b * NTOK + q) * DM + h * HD;
    #pragma unroll
    for (int r = 0; r < 4; ++r) {
        op[grp * 4 + r]      = f2bf(o0[r] * inv);
        op[16 + grp * 4 + r] = f2bf(o1[r] * inv);
        op[32 + grp * 4 + r] = f2bf(o2[r] * inv);
        op[48 + grp * 4 + r] = f2bf(o3[r] * inv);
    }
}

// ---------------- deferred mask4 rows [0, DEFER_ROWS): overwrite scratch last ----------------
__global__ void k_mask4b(const uint32_t* __restrict__ ebits, const uint32_t* __restrict__ colbits,
                         float* __restrict__ mout) {
    mask_row(blockIdx.x, ebits, colbits, mout);
}

// ---------------- output projection GEMM (f32 out) ----------------
__global__ __launch_bounds__(256) void k_gemm_o(const unsigned short* __restrict__ A,
                                                const unsigned short* __restrict__ WT,
                                                const float* __restrict__ bias,
                                                float* __restrict__ out) {
    int lane = threadIdx.x & 63, w = threadIdx.x >> 6;
    int l15 = lane & 15, grp = lane >> 4;
    int mbase = blockIdx.x * 64 + w * 16;
    int nbase = blockIdx.y * 64;
    f32x4 acc0 = {0,0,0,0}, acc1 = {0,0,0,0}, acc2 = {0,0,0,0}, acc3 = {0,0,0,0};
    const unsigned short* ap = A + (size_t)(mbase + l15) * DM + grp * 8;
    const unsigned short* bp = WT + (size_t)(nbase + l15) * DM + grp * 8;
    #pragma unroll
    for (int k0 = 0; k0 < DM; k0 += 32) {
        bf16x8 af = *(const bf16x8*)(ap + k0);
        acc0 = MFMA16(af, *(const bf16x8*)(bp + k0), acc0, 0, 0, 0);
        acc1 = MFMA16(af, *(const bf16x8*)(bp + 16 * DM + k0), acc1, 0, 0, 0);
        acc2 = MFMA16(af, *(const bf16x8*)(bp + 32 * DM + k0), acc2, 0, 0, 0);
        acc3 = MFMA16(af, *(const bf16x8*)(bp + 48 * DM + k0), acc3, 0, 0, 0);
    }
    f32x4 accs[4] = {acc0, acc1, acc2, acc3};
    #pragma unroll
    for (int ct = 0; ct < 4; ++ct) {
        #pragma unroll
        for (int r = 0; r < 4; ++r) {
            int m = mbase + grp * 4 + r;
            int n = nbase + ct * 16 + l15;
            out[(size_t)m * DM + n] = accs[ct][r] + bias[n];
        }
    }
}

extern "C" void kernel_launch(void* const* d_in, const int* in_sizes, int n_in,
                              void* d_out, int out_size, void* d_ws, size_t ws_size,
                              hipStream_t stream) {
    const float* x   = (const float*)d_in[0];
    const int*   ei  = (const int*)d_in[1];          // int64 in reference -> int32 here
    const float* Wq  = (const float*)d_in[2];
    const float* bq  = (const float*)d_in[3];
    const float* Wk  = (const float*)d_in[4];
    const float* bk  = (const float*)d_in[5];
    const float* Wv  = (const float*)d_in[6];
    const float* bv  = (const float*)d_in[7];
    const float* Wo  = (const float*)d_in[8];
    const float* bo  = (const float*)d_in[9];
    const float* Wg1 = (const float*)d_in[10];
    const float* bg1 = (const float*)d_in[11];
    const float* Wg2 = (const float*)d_in[12];
    const float* bg2 = (const float*)d_in[13];

    float* out0  = (float*)d_out;
    float* mask4 = out0 + (size_t)NB * NTOK * DM;

    // Large scratch lives in the FIRST 26.25 MB (= DEFER_ROWS rows) of the mask4
    // output region. k_attn_mask4 writes all other rows (overlapped with attention);
    // k_mask4b rewrites the scratch rows last. Every byte written every call.
    uint8_t* big = (uint8_t*)mask4;
    unsigned short* xbf   = (unsigned short*)(big);                 // 4 MB
    unsigned short* qbf   = (unsigned short*)(big + (4u  << 20));   // 4 MB
    unsigned short* kbf   = (unsigned short*)(big + (8u  << 20));   // 4 MB
    unsigned short* vt    = (unsigned short*)(big + (12u << 20));   // 4 MB
    unsigned short* wt    = (unsigned short*)(big + (16u << 20));   // 512 KB (4 x W^T)
    uint32_t*       scol  = (uint32_t*)(big + (16u << 20) + (512u << 10)); // 1 MB
    unsigned short* aoutb = (unsigned short*)(big + (17u << 20) + (512u << 10)); // 4 MB -> ends 21.5 MB < 26.25 MB

    // Small scratch in d_ws (~564 KB)
    uint8_t* ws = (uint8_t*)d_ws;
    uint32_t* cursor  = (uint32_t*)(ws);               // 8 KB  (atomic; zeroed by k_prep)
    uint32_t* ebits   = (uint32_t*)(ws + (16u << 10)); // 512 KB (atomic; zeroed by k_prep)
    uint32_t* colbits = (uint32_t*)(ws + (528u << 10));// 256 B (fully written)
    float*    topo    = (float*)(ws + (532u << 10));   // 32 KB (fully written)

    k_prep<<<3204, 256, 0, stream>>>(x, xbf, Wq, Wk, Wv, Wo, wt, (float4*)ws);
    k_edges<<<256, 256, 0, stream>>>(ei, cursor, scol, ebits);
    k_gnn_qkv<<<3584, 256, 0, stream>>>(x, cursor, scol, Wg1, bg1, Wg2, bg2, topo,
                                        xbf, wt, bq, bk, bv, qbf, kbf, vt);
    k_topk<<<dim3(8, 4), 256, 0, stream>>>(topo, colbits);
    k_attn_mask4<<<512 + (32768 - DEFER_ROWS), 256, 0, stream>>>(qbf, kbf, vt, ebits, colbits,
                                                                 aoutb, mask4);
    k_gemm_o<<<dim3(128, 4), 256, 0, stream>>>(aoutb, wt + 196608, bo, out0);
    k_mask4b<<<DEFER_ROWS, 256, 0, stream>>>(ebits, colbits, mask4);
}